// Round 1
// baseline (68.758 us; speedup 1.0000x reference)
//
#include <hip/hip_runtime.h>

#define TPB 256
#define MAXB 512
#define MAXPOS 64  // unique positives per sample <= K; generous cap

// One block handles samples b = blockIdx.x, blockIdx.x + gridDim.x, ...
// Per sample: compact unique positive scores into LDS, negatives accumulate
// hinge terms. Per-block double partial sums written to ws (write, not
// atomic-add, so 0xAA poisoning needs no init pass).
__global__ void mlrl_main(const float* __restrict__ scores,
                          const int* __restrict__ idx,
                          const int* __restrict__ ndev,
                          int total_scores, int total_idx,
                          double* __restrict__ partial_loss,
                          double* __restrict__ partial_pairs) {
    const int D = *ndev;                 // 256
    const int B = total_scores / D;      // 2048
    const int K = total_idx / B;         // 8

    __shared__ float sh_pos[MAXPOS];
    __shared__ int   sh_cnt;

    double loss  = 0.0;
    double pairs = 0.0;

    for (int b = blockIdx.x; b < B; b += gridDim.x) {
        if (threadIdx.x == 0) sh_cnt = 0;
        __syncthreads();

        const int*   row_idx = idx    + (long)b * K;
        const float* row_s   = scores + (long)b * D;

        // Pass 1: gather unique positive scores (set semantics: membership test
        // per d collapses duplicate indices).
        for (int d = threadIdx.x; d < D; d += blockDim.x) {
            bool is_pos = false;
            for (int k = 0; k < K; ++k) is_pos |= (row_idx[k] == d);
            if (is_pos) {
                int p = atomicAdd(&sh_cnt, 1);
                if (p < MAXPOS) sh_pos[p] = row_s[d];
            }
        }
        __syncthreads();
        const int P = sh_cnt;

        // Pass 2: negatives accumulate hinge over the P unique positives.
        for (int d = threadIdx.x; d < D; d += blockDim.x) {
            bool is_pos = false;
            for (int k = 0; k < K; ++k) is_pos |= (row_idx[k] == d);
            if (!is_pos) {
                const float s = row_s[d];
                for (int p = 0; p < P; ++p) {
                    float v = s - sh_pos[p] + 1.0f;
                    if (v > 0.0f) loss += (double)v;
                }
            }
        }
        if (threadIdx.x == 0) pairs += (double)(D - P) * (double)P;
        __syncthreads();   // protect sh_cnt reset of next iteration
    }

    // Block reduction (256 doubles in LDS, tree).
    __shared__ double red[TPB];
    red[threadIdx.x] = loss;
    __syncthreads();
    for (int s = TPB / 2; s > 0; s >>= 1) {
        if (threadIdx.x < s) red[threadIdx.x] += red[threadIdx.x + s];
        __syncthreads();
    }
    if (threadIdx.x == 0) {
        partial_loss[blockIdx.x]  = red[0];
        partial_pairs[blockIdx.x] = pairs;
    }
}

__global__ void mlrl_finalize(const double* __restrict__ partial_loss,
                              const double* __restrict__ partial_pairs,
                              int n, float* __restrict__ out) {
    __shared__ double sl[TPB];
    __shared__ double sp[TPB];
    double l = 0.0, p = 0.0;
    for (int i = threadIdx.x; i < n; i += blockDim.x) {
        l += partial_loss[i];
        p += partial_pairs[i];
    }
    sl[threadIdx.x] = l;
    sp[threadIdx.x] = p;
    __syncthreads();
    for (int s = TPB / 2; s > 0; s >>= 1) {
        if (threadIdx.x < s) {
            sl[threadIdx.x] += sl[threadIdx.x + s];
            sp[threadIdx.x] += sp[threadIdx.x + s];
        }
        __syncthreads();
    }
    if (threadIdx.x == 0) {
        double L = sl[0], P = sp[0];
        out[0] = (P > 0.0) ? (float)(L / (P < 1.0 ? 1.0 : P)) : 0.0f;
    }
}

extern "C" void kernel_launch(void* const* d_in, const int* in_sizes, int n_in,
                              void* d_out, int out_size, void* d_ws, size_t ws_size,
                              hipStream_t stream) {
    const float* scores = (const float*)d_in[0];
    const int*   idx    = (const int*)d_in[1];
    const int*   ndev   = (const int*)d_in[2];  // num_developers, device scalar
    float* out = (float*)d_out;

    const int total_scores = in_sizes[0];  // B*D
    const int total_idx    = in_sizes[1];  // B*K

    // Partials live in ws: [MAXB loss doubles][MAXB pairs doubles].
    int nblocks = MAXB;
    size_t need = (size_t)nblocks * 2 * sizeof(double);
    if (ws_size < need) {
        nblocks = (int)(ws_size / (2 * sizeof(double)));
        if (nblocks < 1) nblocks = 1;
    }
    double* partial_loss  = (double*)d_ws;
    double* partial_pairs = partial_loss + nblocks;

    mlrl_main<<<nblocks, TPB, 0, stream>>>(scores, idx, ndev,
                                           total_scores, total_idx,
                                           partial_loss, partial_pairs);
    mlrl_finalize<<<1, TPB, 0, stream>>>(partial_loss, partial_pairs, nblocks, out);
}

// Round 2
// 66.569 us; speedup vs baseline: 1.0329x; 1.0329x over previous
//
#include <hip/hip_runtime.h>

#define TPB 256
#define MAXK 64   // unique positives per sample (K=8 in the bench; generous cap)

// One block per sample. Threads 0..K-1 stage indices + gather positive scores
// (dedupe via rank comparison — duplicate indices collapse like a set, no
// atomics). Then each thread d in [0,D) does a K-way membership test and, if
// negative, accumulates relu(s_neg - s_pos + 1) over the valid positives.
// Block partial (loss, pairs) written to ws as float2 — plain store, so the
// 0xAA ws poison needs no init pass.
__global__ __launch_bounds__(TPB) void mlrl_main(
        const float* __restrict__ scores,
        const int* __restrict__ idx,
        const int* __restrict__ ndev,
        int total_scores, int total_idx,
        float2* __restrict__ partials) {
    const int D = *ndev;                 // 256
    const int B = total_scores / D;      // 2048
    const int K = total_idx / B;         // 8

    __shared__ int   sh_idx[MAXK];
    __shared__ float sh_pos[MAXK];
    __shared__ int   sh_valid[MAXK];

    float loss  = 0.0f;
    float pairs = 0.0f;

    for (int b = blockIdx.x; b < B; b += gridDim.x) {
        const long row = (long)b * D;

        // Stage indices.
        if (threadIdx.x < K) sh_idx[threadIdx.x] = idx[(long)b * K + threadIdx.x];
        __syncthreads();
        // Dedupe (keep first occurrence) + gather positive scores.
        if (threadIdx.x < K) {
            const int my = sh_idx[threadIdx.x];
            int valid = 1;
            for (int j = 0; j < (int)threadIdx.x; ++j)
                if (sh_idx[j] == my) valid = 0;
            sh_valid[threadIdx.x] = valid;
            sh_pos[threadIdx.x]   = scores[row + my];
        }
        __syncthreads();

        int P = 0;
        for (int k = 0; k < K; ++k) P += sh_valid[k];

        for (int d = threadIdx.x; d < D; d += blockDim.x) {
            bool is_pos = false;
            for (int k = 0; k < K; ++k) is_pos |= (sh_idx[k] == d);
            if (!is_pos) {
                const float s = scores[row + d] + 1.0f;  // margin folded in
                for (int k = 0; k < K; ++k) {
                    if (sh_valid[k]) {
                        float v = s - sh_pos[k];
                        loss += (v > 0.0f) ? v : 0.0f;
                    }
                }
            }
        }
        if (threadIdx.x == 0) pairs += (float)((D - P) * P);
        __syncthreads();   // protect LDS re-staging on next iteration
    }

    // Wave (64-lane) shuffle reduction, then 4 wave-partials via LDS.
    for (int off = 32; off > 0; off >>= 1) {
        loss  += __shfl_down(loss,  off);
        pairs += __shfl_down(pairs, off);
    }
    __shared__ float2 red[TPB / 64];
    const int wave = threadIdx.x >> 6;
    const int lane = threadIdx.x & 63;
    if (lane == 0) red[wave] = make_float2(loss, pairs);
    __syncthreads();
    if (threadIdx.x == 0) {
        float2 acc = red[0];
        for (int w = 1; w < TPB / 64; ++w) { acc.x += red[w].x; acc.y += red[w].y; }
        partials[blockIdx.x] = acc;
    }
}

__global__ __launch_bounds__(TPB) void mlrl_finalize(
        const float2* __restrict__ partials, int n, float* __restrict__ out) {
    double l = 0.0, p = 0.0;
    for (int i = threadIdx.x; i < n; i += blockDim.x) {
        float2 v = partials[i];
        l += (double)v.x;
        p += (double)v.y;
    }
    for (int off = 32; off > 0; off >>= 1) {
        l += __shfl_down(l, off);
        p += __shfl_down(p, off);
    }
    __shared__ double sl[TPB / 64], sp[TPB / 64];
    const int wave = threadIdx.x >> 6;
    const int lane = threadIdx.x & 63;
    if (lane == 0) { sl[wave] = l; sp[wave] = p; }
    __syncthreads();
    if (threadIdx.x == 0) {
        double L = 0.0, P = 0.0;
        for (int w = 0; w < TPB / 64; ++w) { L += sl[w]; P += sp[w]; }
        out[0] = (P > 0.0) ? (float)(L / (P < 1.0 ? 1.0 : P)) : 0.0f;
    }
}

extern "C" void kernel_launch(void* const* d_in, const int* in_sizes, int n_in,
                              void* d_out, int out_size, void* d_ws, size_t ws_size,
                              hipStream_t stream) {
    const float* scores = (const float*)d_in[0];
    const int*   idx    = (const int*)d_in[1];
    const int*   ndev   = (const int*)d_in[2];  // num_developers, device scalar
    float* out = (float*)d_out;

    const int total_scores = in_sizes[0];  // B*D
    const int total_idx    = in_sizes[1];  // B*K

    // Host-side grid sizing: assume D=256 (bench shape); grid-stride in-kernel
    // keeps correctness if D differs, and blocks past B write zero partials.
    int nblocks = total_scores / 256;
    if (nblocks < 1) nblocks = 1;
    size_t need = (size_t)nblocks * sizeof(float2);
    if (need > ws_size) nblocks = (int)(ws_size / sizeof(float2));

    float2* partials = (float2*)d_ws;

    mlrl_main<<<nblocks, TPB, 0, stream>>>(scores, idx, ndev,
                                           total_scores, total_idx, partials);
    mlrl_finalize<<<1, TPB, 0, stream>>>(partials, nblocks, out);
}